// Round 2
// baseline (542.606 us; speedup 1.0000x reference)
//
#include <hip/hip_runtime.h>
#include <hip/hip_bf16.h>
#include <stdint.h>

typedef __attribute__((ext_vector_type(8)))  short   short8;
typedef __attribute__((ext_vector_type(16))) float   floatx16;

#define B_    64
#define CIN   64
#define COUT  128
#define T_    300
#define V_    25
#define TV    (T_ * V_)          // 7500
#define NRED  (B_ * T_ * V_)     // 480000 elements per channel
#define NSLOTS 32
#define NT    12                 // t's per block strip; 300/12 = 25 chunks
#define EPS   1e-5f

// ws layout (bytes):
//   [0,      16384)  wsW   : 8192 bf16  W A-fragments
//   [16384,  18432)  wsAdj : 1024 bf16  adj B-fragments (zero-padded to 32x32)
//   [18432,  34816)  psum  : 32*128 f32 partial sums
//   [34816,  51200)  psq   : 32*128 f32 partial sum-of-squares
//   [51200,  51712)  scale : 128 f32
//   [51712,  52224)  shift : 128 f32
//   [65536,  65536 + 78643200)  gfrag : G in B-frag order, bf16
#define GFRAG_OFF   65536
#define GFRAG_BYTES ((size_t)B_ * T_ * 4 * 64 * 8 * 2)   // 78,643,200

__device__ __forceinline__ unsigned short f2bf(float f) {
    union { float f; uint32_t u; } c; c.f = f;
    uint32_t u = c.u;
    u += 0x7FFFu + ((u >> 16) & 1u);   // round-to-nearest-even
    return (unsigned short)(u >> 16);
}

// pack two f32 -> one 32-bit word holding 2 bf16 (low = a), via v_cvt_pk_bf16_f32
__device__ __forceinline__ uint32_t pk2(float a, float b) {
    union { __hip_bfloat162 h; uint32_t u; } c;
    c.h = __float22bfloat162_rn(make_float2(a, b));
    return c.u;
}

__device__ __forceinline__ floatx16 fzero16() {
    floatx16 z;
#pragma unroll
    for (int i = 0; i < 16; ++i) z[i] = 0.f;
    return z;
}

// ---- x -> MFMA A-fragments for the two c-tiles (bf16) -----------------------
// A-frag (32x32x16): lane holds A[m=l&31][k=8*(l>>5)+j]; k-step 0: v=8q+j,
// k-step 1: v=16+8q+j (zero-padded past v=24).
__device__ __forceinline__ void build_xfrags(const float* __restrict__ x,
                                             int b, int t, int ln, int q,
                                             short8 xa[2][2]) {
#pragma unroll
    for (int ct = 0; ct < 2; ++ct) {
        const float* xr = x + ((size_t)(b * CIN + 32 * ct + ln) * T_ + t) * V_;
        union { short8 s; uint32_t u[4]; } A0, A1;
#pragma unroll
        for (int p = 0; p < 4; ++p)
            A0.u[p] = pk2(xr[8 * q + 2 * p], xr[8 * q + 2 * p + 1]);
        if (q == 0) {
#pragma unroll
            for (int p = 0; p < 4; ++p)
                A1.u[p] = pk2(xr[16 + 2 * p], xr[16 + 2 * p + 1]);
        } else {
            A1.u[0] = pk2(xr[24], 0.f);
            A1.u[1] = 0; A1.u[2] = 0; A1.u[3] = 0;
        }
        xa[ct][0] = A0.s;
        xa[ct][1] = A1.s;
    }
}

// ---- G = X @ adjp, then C-layout -> B-frag layout via lane^32 exchange ------
// C-layout: lane holds G[m=(r&3)+8*(r>>2)+4q][v=l&31].
// B-frag kk: lane needs G[c=16kk+8q+j][v=l&31], j=0..7.  Same v->lane mapping;
// missing c's are in the partner half-wave's registers (lane^32).
__device__ __forceinline__ void compute_g_frags(const short8 xa[2][2],
                                                const short8 af[2], int q,
                                                short8 frag[4]) {
#pragma unroll
    for (int ct = 0; ct < 2; ++ct) {
        floatx16 g = fzero16();
        g = __builtin_amdgcn_mfma_f32_32x32x16_bf16(xa[ct][0], af[0], g, 0, 0, 0);
        g = __builtin_amdgcn_mfma_f32_32x32x16_bf16(xa[ct][1], af[1], g, 0, 0, 0);
        uint32_t pk[8], pp[8];
#pragma unroll
        for (int i = 0; i < 8; ++i) pk[i] = pk2(g[2 * i], g[2 * i + 1]);
#pragma unroll
        for (int i = 0; i < 8; ++i) pp[i] = (uint32_t)__shfl_xor((int)pk[i], 32, 64);
#pragma unroll
        for (int kkl = 0; kkl < 2; ++kkl) {
            union { short8 s; uint32_t u[4]; } F;
            F.u[0] = q ? pp[4 * kkl + 2] : pk[4 * kkl];
            F.u[1] = q ? pp[4 * kkl + 3] : pk[4 * kkl + 1];
            F.u[2] = q ? pk[4 * kkl + 2] : pp[4 * kkl];
            F.u[3] = q ? pk[4 * kkl + 3] : pp[4 * kkl + 1];
            frag[2 * ct + kkl] = F.s;
        }
    }
}

// ---- one-time pack of W (A-frags) and adj (B-frags) -------------------------
__global__ void pack_kernel(const float* __restrict__ W, const float* __restrict__ adj,
                            unsigned short* __restrict__ wsW, unsigned short* __restrict__ wsAdj) {
    int stride = blockDim.x * gridDim.x;
    for (int idx = threadIdx.x + blockIdx.x * blockDim.x; idx < 8192; idx += stride) {
        int j  = idx & 7;
        int l  = (idx >> 3) & 63;
        int kk = (idx >> 9) & 3;
        int w  = idx >> 11;
        int o  = 32 * w + (l & 31);
        int c  = 16 * kk + 8 * (l >> 5) + j;
        wsW[idx] = f2bf(W[o * CIN + c]);
    }
    for (int idx = threadIdx.x + blockIdx.x * blockDim.x; idx < 1024; idx += stride) {
        int j = idx & 7;
        int l = (idx >> 3) & 63;
        int s = idx >> 9;
        int k = 16 * s + 8 * (l >> 5) + j;   // v index
        int n = l & 31;                       // w index
        float v = (k < V_ && n < V_) ? adj[k * V_ + n] : 0.f;
        wsAdj[idx] = f2bf(v);
    }
}

// ---- pass 1: per-channel sum / sumsq (and stash G-frags) --------------------
// Block 256 = 4 waves; wave w owns o-tile w (rows 32w..32w+31).
// Grid (25, 64): 12 consecutive t per block, b = blockIdx.y. No LDS, no barriers.
template <bool STASH>
__global__ __launch_bounds__(256, 3) void pass1_kernel(
    const float* __restrict__ x,
    const unsigned short* __restrict__ wsW,
    const unsigned short* __restrict__ wsAdj,
    float* __restrict__ psum, float* __restrict__ psq,
    unsigned short* __restrict__ gfrag)
{
    const int tid  = threadIdx.x;
    const int wave = tid >> 6;
    const int lane = tid & 63;
    const int q    = lane >> 5;
    const int ln   = lane & 31;
    const int b    = blockIdx.y;
    const int tbase = blockIdx.x * NT;

    short8 wf[4];
#pragma unroll
    for (int kk = 0; kk < 4; ++kk)
        wf[kk] = ((const short8*)wsW)[(wave * 4 + kk) * 64 + lane];
    short8 af[2];
#pragma unroll
    for (int s = 0; s < 2; ++s)
        af[s] = ((const short8*)wsAdj)[s * 64 + lane];

    float sums[16], sqs[16];
#pragma unroll
    for (int r = 0; r < 16; ++r) { sums[r] = 0.f; sqs[r] = 0.f; }

    for (int i = 0; i < NT; ++i) {
        const int t = tbase + i;
        short8 xa[2][2];
        build_xfrags(x, b, t, ln, q, xa);
        short8 frag[4];
        compute_g_frags(xa, af, q, frag);

        if (STASH && wave == 0) {
            short8* gp = (short8*)gfrag + (size_t)(b * T_ + t) * 4 * 64 + lane;
#pragma unroll
            for (int kk = 0; kk < 4; ++kk) gp[kk * 64] = frag[kk];
        }

        floatx16 acc = fzero16();
#pragma unroll
        for (int kk = 0; kk < 4; ++kk)
            acc = __builtin_amdgcn_mfma_f32_32x32x16_bf16(wf[kk], frag[kk], acc, 0, 0, 0);
#pragma unroll
        for (int r = 0; r < 16; ++r) {
            sums[r] += acc[r];
            sqs[r]  += acc[r] * acc[r];
        }
    }

    // reduce over the 32 v-lanes of each half-wave, one atomic per channel
#pragma unroll
    for (int r = 0; r < 16; ++r) {
        float s = sums[r], ss = sqs[r];
#pragma unroll
        for (int m = 1; m <= 16; m <<= 1) {
            s  += __shfl_xor(s,  m, 64);
            ss += __shfl_xor(ss, m, 64);
        }
        sums[r] = s; sqs[r] = ss;
    }
    if (ln == 0) {
        int slot = (blockIdx.y * 25 + blockIdx.x) & (NSLOTS - 1);
#pragma unroll
        for (int r = 0; r < 16; ++r) {
            int ch = 32 * wave + (r & 3) + 8 * (r >> 2) + 4 * q;
            atomicAdd(&psum[slot * COUT + ch], sums[r]);
            atomicAdd(&psq [slot * COUT + ch], sqs[r]);
        }
    }
}

// ---- stats: fold partials into per-channel scale/shift ----------------------
__global__ void stats_kernel(const float* __restrict__ psum, const float* __restrict__ psq,
                             const float* __restrict__ gamma, const float* __restrict__ beta,
                             float* __restrict__ scale, float* __restrict__ shift) {
    int o = threadIdx.x;   // 128 threads
    float s = 0.f, ss = 0.f;
    for (int k = 0; k < NSLOTS; ++k) {
        s  += psum[k * COUT + o];
        ss += psq [k * COUT + o];
    }
    float mean = s / (float)NRED;
    float var  = ss / (float)NRED - mean * mean;
    float inv  = rsqrtf(var + EPS);
    float scv  = gamma[o] * inv;
    scale[o] = scv;
    shift[o] = beta[o] - mean * scv;
}

// ---- pass 2: Y = W@G, normalize + relu, store -------------------------------
template <bool STASH>
__global__ __launch_bounds__(256, 3) void pass2_kernel(
    const float* __restrict__ x,
    const unsigned short* __restrict__ wsW,
    const unsigned short* __restrict__ wsAdj,
    const unsigned short* __restrict__ gfrag,
    const float* __restrict__ scale, const float* __restrict__ shift,
    float* __restrict__ out)
{
    const int tid  = threadIdx.x;
    const int wave = tid >> 6;
    const int lane = tid & 63;
    const int q    = lane >> 5;
    const int ln   = lane & 31;
    const int b    = blockIdx.y;
    const int tbase = blockIdx.x * NT;

    short8 wf[4];
#pragma unroll
    for (int kk = 0; kk < 4; ++kk)
        wf[kk] = ((const short8*)wsW)[(wave * 4 + kk) * 64 + lane];
    short8 af[2];
    if (!STASH) {
#pragma unroll
        for (int s = 0; s < 2; ++s)
            af[s] = ((const short8*)wsAdj)[s * 64 + lane];
    }

    float sc[16], sh[16];
#pragma unroll
    for (int r = 0; r < 16; ++r) {
        int row = 32 * wave + (r & 3) + 8 * (r >> 2) + 4 * q;
        sc[r] = scale[row];
        sh[r] = shift[row];
    }

    for (int i = 0; i < NT; ++i) {
        const int t = tbase + i;
        short8 frag[4];
        if (STASH) {
            const short8* gp = (const short8*)gfrag + (size_t)(b * T_ + t) * 4 * 64 + lane;
#pragma unroll
            for (int kk = 0; kk < 4; ++kk) frag[kk] = gp[kk * 64];
        } else {
            short8 xa[2][2];
            build_xfrags(x, b, t, ln, q, xa);
            compute_g_frags(xa, af, q, frag);
        }

        floatx16 acc = fzero16();
#pragma unroll
        for (int kk = 0; kk < 4; ++kk)
            acc = __builtin_amdgcn_mfma_f32_32x32x16_bf16(wf[kk], frag[kk], acc, 0, 0, 0);

        if (ln < V_) {
            float* obase = out + ((size_t)(b * COUT + 32 * wave) * T_ + t) * V_ + ln;
#pragma unroll
            for (int r = 0; r < 16; ++r) {
                int row = (r & 3) + 8 * (r >> 2) + 4 * q;
                float v = sc[r] * acc[r] + sh[r];
                obase[(size_t)row * TV] = v > 0.f ? v : 0.f;
            }
        }
    }
}

extern "C" void kernel_launch(void* const* d_in, const int* in_sizes, int n_in,
                              void* d_out, int out_size, void* d_ws, size_t ws_size,
                              hipStream_t stream) {
    const float* x     = (const float*)d_in[0];
    const float* adj   = (const float*)d_in[1];
    const float* W     = (const float*)d_in[2];
    // d_in[3] = conv bias: cancelled exactly by training-mode BatchNorm -> unused
    const float* gamma = (const float*)d_in[4];
    const float* beta  = (const float*)d_in[5];
    float* out = (float*)d_out;

    char* ws = (char*)d_ws;
    unsigned short* wsW   = (unsigned short*)(ws);
    unsigned short* wsAdj = (unsigned short*)(ws + 16384);
    float* psum  = (float*)(ws + 18432);
    float* psq   = (float*)(ws + 34816);
    float* scale = (float*)(ws + 51200);
    float* shift = (float*)(ws + 51712);
    unsigned short* gfrag = (unsigned short*)(ws + GFRAG_OFF);

    const bool stash = ws_size >= (size_t)GFRAG_OFF + GFRAG_BYTES;

    hipMemsetAsync(psum, 0, 2 * NSLOTS * COUT * sizeof(float), stream);
    pack_kernel<<<8, 256, 0, stream>>>(W, adj, wsW, wsAdj);

    dim3 grid(T_ / NT, B_);
    if (stash) {
        pass1_kernel<true><<<grid, 256, 0, stream>>>(x, wsW, wsAdj, psum, psq, gfrag);
        stats_kernel<<<1, 128, 0, stream>>>(psum, psq, gamma, beta, scale, shift);
        pass2_kernel<true><<<grid, 256, 0, stream>>>(x, wsW, wsAdj, gfrag, scale, shift, out);
    } else {
        pass1_kernel<false><<<grid, 256, 0, stream>>>(x, wsW, wsAdj, psum, psq, gfrag);
        stats_kernel<<<1, 128, 0, stream>>>(psum, psq, gamma, beta, scale, shift);
        pass2_kernel<false><<<grid, 256, 0, stream>>>(x, wsW, wsAdj, gfrag, scale, shift, out);
    }
}